// Round 10
// baseline (30.476 us; speedup 1.0000x reference)
//
#include <hip/hip_runtime.h>
#include <math.h>

#define TT 512
#define KP 4

typedef unsigned long long u64;

// Block-wide LDS barrier: waits DS ops, leaves global stores unfenced.
#define SYNCL() asm volatile("s_waitcnt lgkmcnt(0)\n\ts_barrier" ::: "memory")
// In-wave DS fence (cross-lane via LDS within one wave).
#define SYNCW() do { asm volatile("s_waitcnt lgkmcnt(0)" ::: "memory"); \
                     __builtin_amdgcn_sched_barrier(0); } while (0)

// one block per sequence row. 256 threads = 4 waves.
__global__ __launch_bounds__(256) void periodicity_kernel(const float* __restrict__ x,
                                                          float* __restrict__ out) {
    // XCD-grouped swizzle: line-sharing groups (16 consecutive bn) colocate per XCD.
    const int bn   = (blockIdx.x & 7) * 256 + (blockIdx.x >> 3);   // bijective, 2048 = 8*256
    const int tid  = threadIdx.x;    // 0..255
    const int lane = tid & 63;
    const int wid  = tid >> 6;
    const int b = bn >> 6;
    const int n = bn & 63;

    __shared__ float2 tw[TT];                       // tw[m] = e^{-2*pi*i*m/512}
    __shared__ __align__(16) float row[TT];         // natural order
    __shared__ __align__(16) float2 buf[TT];        // FFT working buffer
    __shared__ __align__(16) u64 keys[256];         // (mag_bits<<32)|(256-f), any order
    __shared__ double candV8[8];

    // ---- twiddles (one sincosf/thread) ----
    float sv, cv;
    sincosf((float)(2.0 * M_PI / 512.0) * (float)tid, &sv, &cv);
    tw[tid]       = make_float2(cv, -sv);
    tw[tid + 256] = make_float2(-cv, sv);

    // ---- load row (stride-64 column) + folded radix-2 first DIF stage ----
    const float* xb = x + (size_t)b * (TT * 64) + n;
    {
        float v0 = xb[(size_t)tid * 64];
        float v1 = xb[(size_t)(tid + 256) * 64];
        row[tid] = v0;  row[tid + 256] = v1;
        float sum = v0 + v1, dif = v0 - v1;
        buf[tid]       = make_float2(sum, 0.f);
        buf[tid + 256] = make_float2(dif * cv, -dif * sv);
    }
    SYNCL();   // barrier 1: buf/row/tw ready

    // ---- wave-local FFT: wave h owns 256-half h; in-wave fences only ----
    if (wid < 2) {
        const int h = wid;
        float2* bb = &buf[h << 8];

        #pragma unroll
        for (int stg = 0; stg < 3; ++stg) {
            const int Q  = 64 >> (2 * stg);          // 64,16,4
            const int g  = lane >> (6 - 2 * stg);
            const int i  = lane & (Q - 1);
            const int base = g * (Q << 2) + i;
            float2 x0 = bb[base],         x1 = bb[base + Q];
            float2 x2 = bb[base + 2 * Q], x3 = bb[base + 3 * Q];
            float2 A  = make_float2(x0.x + x2.x, x0.y + x2.y);
            float2 Bm = make_float2(x0.x - x2.x, x0.y - x2.y);
            float2 Cc = make_float2(x1.x + x3.x, x1.y + x3.y);
            float2 D  = make_float2(x1.x - x3.x, x1.y - x3.y);
            float2 y0 = make_float2(A.x + Cc.x, A.y + Cc.y);
            float2 y2 = make_float2(A.x - Cc.x, A.y - Cc.y);
            float2 y1 = make_float2(Bm.x + D.y, Bm.y - D.x);   // Bm - i*D
            float2 y3 = make_float2(Bm.x - D.y, Bm.y + D.x);   // Bm + i*D
            const int m = i << (1 + 2 * stg);
            float2 t1 = tw[m], t2 = tw[2 * m], t3 = tw[3 * m];
            bb[base]         = y0;
            bb[base + Q]     = make_float2(y1.x * t1.x - y1.y * t1.y, y1.x * t1.y + y1.y * t1.x);
            bb[base + 2 * Q] = make_float2(y2.x * t2.x - y2.y * t2.y, y2.x * t2.y + y2.y * t2.x);
            bb[base + 3 * Q] = make_float2(y3.x * t3.x - y3.y * t3.y, y3.x * t3.y + y3.y * t3.x);
            SYNCW();
        }

        // stage 3 (Q=1, twiddles=1) fused with mag^2 + vectorized key write
        {
            const int g = lane;
            const int base = g << 2;
            float2 x0 = bb[base],     x1 = bb[base + 1];
            float2 x2 = bb[base + 2], x3 = bb[base + 3];
            float2 A  = make_float2(x0.x + x2.x, x0.y + x2.y);
            float2 Bm = make_float2(x0.x - x2.x, x0.y - x2.y);
            float2 Cc = make_float2(x1.x + x3.x, x1.y + x3.y);
            float2 D  = make_float2(x1.x - x3.x, x1.y - x3.y);
            float2 y0 = make_float2(A.x + Cc.x, A.y + Cc.y);
            float2 y2 = make_float2(A.x - Cc.x, A.y - Cc.y);
            float2 y1 = make_float2(Bm.x + D.y, Bm.y - D.x);
            float2 y3 = make_float2(Bm.x - D.y, Bm.y + D.x);
            const int revg = ((g & 3) << 4) | (((g >> 2) & 3) << 2) | ((g >> 4) & 3);
            const int f0 = 2 * revg + h;
            float m0 = y0.x * y0.x + y0.y * y0.y;
            float m1 = y1.x * y1.x + y1.y * y1.y;
            float m2 = y2.x * y2.x + y2.y * y2.y;
            float m3 = y3.x * y3.x + y3.y * y3.y;
            u64 kA, kB;
            if (f0 == 0) {   // only (h=0,g=0): keep f=128 (j=1), f=256 (j=2)
                kA = ((u64)__float_as_uint(m1) << 32) | (u64)(256 - 128);
                kB = ((u64)__float_as_uint(m2) << 32) | (u64)(256 - 256);
            } else {         // keep f0 (j=0), f0+128 (j=1)
                kA = ((u64)__float_as_uint(m0) << 32) | (u64)(256 - f0);
                kB = ((u64)__float_as_uint(m1) << 32) | (u64)(256 - (f0 + 128));
            }
            ulonglong2* kv = (ulonglong2*)keys;
            kv[(h << 6) + g] = make_ulonglong2(kA, kB);
        }
    }
    SYNCL();   // barrier 2: keys ready

    // ---- redundant per-wave top-8 (every wave; results in registers) ----
    int   fbin[8];
    float cmag[8];
    {
        const ulonglong2* kv = (const ulonglong2*)keys;
        ulonglong2 p0v = kv[lane * 2];
        ulonglong2 p1v = kv[lane * 2 + 1];
        u64 k0 = p0v.x, k1 = p0v.y, k2 = p1v.x, k3 = p1v.y;
        #define CSWAP(a, b) { if (a < b) { u64 _t = a; a = b; b = _t; } }
        CSWAP(k0, k1) CSWAP(k2, k3) CSWAP(k0, k2) CSWAP(k1, k3) CSWAP(k1, k2)
        #undef CSWAP
        #pragma unroll
        for (int r = 0; r < 8; ++r) {
            u64 w = k0;
            #pragma unroll
            for (int off = 32; off >= 1; off >>= 1) {
                u64 o = __shfl_xor(w, off);
                if (o > w) w = o;
            }
            if (k0 == w) { k0 = k1; k1 = k2; k2 = k3; k3 = 0; }
            fbin[r] = 256 - (int)(w & 0xff);
            cmag[r] = __uint_as_float((unsigned)(w >> 32));
        }
    }

    // ---- gap check: fp32 ranking provably exact? (uniform across block) ----
    int per[KP], cycv[KP], stv[KP];
    {
        const bool needRefine =
            ((cmag[0] - cmag[1]) <= 1e-4f * cmag[0]) || ((cmag[1] - cmag[2]) <= 1e-4f * cmag[1]) ||
            ((cmag[2] - cmag[3]) <= 1e-4f * cmag[2]) || ((cmag[3] - cmag[4]) <= 1e-4f * cmag[3]);
        int bins[KP];
        if (!needRefine) {
            #pragma unroll
            for (int k = 0; k < KP; ++k) bins[k] = fbin[k];
        } else {
            // ---- f64 refine of the 8 candidates (rare; exact ranking) ----
            {
                const int cid = tid >> 5;        // candidate 0..7
                const int sub = tid & 31;
                int fc;
                switch (cid) {                   // static indices (rule #20)
                    case 0: fc = fbin[0]; break;
                    case 1: fc = fbin[1]; break;
                    case 2: fc = fbin[2]; break;
                    case 3: fc = fbin[3]; break;
                    case 4: fc = fbin[4]; break;
                    case 5: fc = fbin[5]; break;
                    case 6: fc = fbin[6]; break;
                    default: fc = fbin[7]; break;
                }
                const int t0 = sub * 16;
                const double W = 6.2831853071795864769 / 512.0;
                double zr, zi, wr, wi;
                sincos(W * (double)((fc * t0) & 511), &zi, &zr);
                sincos(W * (double)fc, &wi, &wr);
                double ar = 0.0, ai = 0.0;
                const float4* r4 = (const float4*)row;
                #pragma unroll
                for (int v4i = 0; v4i < 4; ++v4i) {
                    float4 xv = r4[sub * 4 + v4i];
                    #define STEP(comp)                                   \
                        { double xd = (double)xv.comp;                   \
                          ar = fma(xd, zr, ar); ai = fma(xd, zi, ai);    \
                          double tq = zr * wr - zi * wi;                 \
                          zi = fma(zr, wi, zi * wr); zr = tq; }
                    STEP(x) STEP(y) STEP(z) STEP(w)
                    #undef STEP
                }
                #pragma unroll
                for (int off = 16; off >= 1; off >>= 1) {
                    ar += __shfl_xor(ar, off);
                    ai += __shfl_xor(ai, off);
                }
                if (sub == 0) candV8[cid] = ar * ar + ai * ai;
            }
            SYNCL();
            unsigned chosen = 0;
            #pragma unroll
            for (int k = 0; k < KP; ++k) {
                double bv = -1.0; int bbin = 0x7fffffff; int bj = 0;
                #pragma unroll
                for (int j = 0; j < 8; ++j) {
                    if (chosen & (1u << j)) continue;
                    double vj = candV8[j];
                    int    bjn = fbin[j];
                    if (vj > bv || (vj == bv && bjn < bbin)) { bv = vj; bbin = bjn; bj = j; }
                }
                chosen |= (1u << bj);
                bins[k] = bbin;
            }
        }
        #pragma unroll
        for (int k = 0; k < KP; ++k) {
            int p = TT / bins[k];
            p = p < 8 ? 8 : (p > 64 ? 64 : p);
            per[k]  = p;
            cycv[k] = TT / p;
            stv[k]  = TT - cycv[k] * p;
        }
    }

    const size_t VOFF = (size_t)2048 * KP * 64 * 64;   // 33,554,432
    if (tid == 0) {
        #pragma unroll
        for (int k = 0; k < KP; ++k) {
            out[VOFF + (size_t)bn * KP + k]        = (float)per[k];
            out[VOFF + 8192 + (size_t)bn * KP + k] = (float)cycv[k];
        }
    }

    // ---- gather + vectorized dense store: values[bn, k, c, p] ----
    float* outv = out + (size_t)bn * (KP * 64 * 64);
    const int c_local = tid >> 4;
    const int p0 = (tid & 15) << 2;
    #pragma unroll
    for (int it = 0; it < 16; ++it) {
        const int k = it >> 2;
        const int c = ((it & 3) << 4) + c_local;
        float4 v = make_float4(0.f, 0.f, 0.f, 0.f);
        const int P = per[k], C = cycv[k], S0 = stv[k];
        if (c < C) {
            const int base = S0 + c * P;
            if (p0 + 3 < P) {
                v.x = row[base + p0];
                v.y = row[base + p0 + 1];
                v.z = row[base + p0 + 2];
                v.w = row[base + p0 + 3];
            } else {
                if (p0     < P) v.x = row[base + p0];
                if (p0 + 1 < P) v.y = row[base + p0 + 1];
                if (p0 + 2 < P) v.z = row[base + p0 + 2];
                if (p0 + 3 < P) v.w = row[base + p0 + 3];
            }
        }
        *(float4*)(outv + (size_t)it * 1024 + (size_t)tid * 4) = v;
    }
}

extern "C" void kernel_launch(void* const* d_in, const int* in_sizes, int n_in,
                              void* d_out, int out_size, void* d_ws, size_t ws_size,
                              hipStream_t stream) {
    const float* x = (const float*)d_in[0];
    float* out = (float*)d_out;
    hipLaunchKernelGGL(periodicity_kernel, dim3(2048), dim3(256), 0, stream, x, out);
}